// Round 9
// baseline (236.838 us; speedup 1.0000x reference)
//
#include <hip/hip_runtime.h>
#include <hip/hip_cooperative_groups.h>

namespace cg = cooperative_groups;

// SpatialAttention: B=4, C=256, H=W=64 -> N=4096, C_qk=32
// d_out: [output (4*256*4096)] ++ [attention_map (4*4096)]  (fp32)
//
// Structure: S=q.kT (K=32) = one mfma_f32_16x16x32_bf16 per 16x16 tile; q,kT
// token-major bf16. Two passes over S (rowsums l, col-means map). gamma==0
// (test data) => output==x; v/PV paths early-exit but are implemented.
// q pre-scaled by log2(e) -> raw v_exp_f32 (2^x); mapB folds -log2(l_i) into
// the MFMA C-init.
// R8: cooperative single-kernel retry with grid 512 + 18.6KB LDS (R7's 1024
// blocks x 37KB LDS failed launch validation). Return code checked; falls back
// to the proven 4-kernel split path (same phase device-functions) on error.

#define B_   4
#define C_   256
#define N_   4096
#define CQK_ 32
#define BCN_ (B_*C_*N_)   // 4194304
#define BN_  (B_*N_)      // 16384
#define TP_  260          // LDS token-row pitch (ushorts)
#define LOG2E 1.4426950408889634f
#define SMEM_BYTES 18560  // max(phaseP 16640, phasePV 18560)

typedef __attribute__((ext_vector_type(8))) short short8v;
typedef __attribute__((ext_vector_type(4))) short short4v;
typedef __attribute__((ext_vector_type(4))) float f32x4;
typedef unsigned short ushort_t;

__device__ __forceinline__ ushort_t f2bf(float f) {
  unsigned u = __builtin_bit_cast(unsigned, f);
  u += 0x7FFFu + ((u >> 16) & 1u);          // round-to-nearest-even
  return (ushort_t)(u >> 16);
}
__device__ __forceinline__ float bf2f(ushort_t h) {
  unsigned u = ((unsigned)h) << 16;
  return __builtin_bit_cast(float, u);
}
__device__ __forceinline__ short8v ld8f(const float* p) {   // 8 fp32 -> bf16 frag
  float4 a = *(const float4*)p, b = *(const float4*)(p + 4);
  short8v r;
  r[0]=f2bf(a.x); r[1]=f2bf(a.y); r[2]=f2bf(a.z); r[3]=f2bf(a.w);
  r[4]=f2bf(b.x); r[5]=f2bf(b.y); r[6]=f2bf(b.z); r[7]=f2bf(b.w);
  return r;
}
__device__ __forceinline__ short8v ld8lds(const ushort_t* p) {  // 8B-aligned LDS
  short4v lo = *(const short4v*)p, hi = *(const short4v*)(p + 4);
  return __builtin_shufflevector(lo, hi, 0, 1, 2, 3, 4, 5, 6, 7);
}

// ---- phase P: out=x copy, q/k (+v) projections, init l/map (512-block grid) --
__device__ __forceinline__ void
phaseP(const float* __restrict__ x, const float* __restrict__ wq,
       const float* __restrict__ bq, const float* __restrict__ wk,
       const float* __restrict__ bk, const float* __restrict__ wv,
       const float* __restrict__ bv, float g0,
       float* __restrict__ out, float* __restrict__ l,
       ushort_t* __restrict__ qb, ushort_t* __restrict__ kb,
       float* __restrict__ v_t, ushort_t* xs, int blk, int tid) {
  int b = blk >> 7, n0 = (blk & 127) << 5;     // 32 tokens/block
#pragma unroll
  for (int it = 0; it < 8; ++it) {             // 2048 float4s: 256ch x 32tok
    int flat = it * 256 + tid;
    int c = flat >> 3, t4 = flat & 7;
    size_t off = ((size_t)(b * C_) + c) * N_ + n0 + t4 * 4;
    float4 v = *(const float4*)(x + off);
    *(float4*)(out + off) = v;
    ushort_t* dst = &xs[(t4 * 4) * TP_ + c];
    dst[0]       = f2bf(v.x);
    dst[TP_]     = f2bf(v.y);
    dst[2 * TP_] = f2bf(v.z);
    dst[3 * TP_] = f2bf(v.w);
  }
  if (blk < 64) {                              // zero l + attention_map
    int idx = blk * 256 + tid;
    l[idx] = 0.0f;
    out[BCN_ + idx] = 0.0f;
  }
  __syncthreads();

  int wave = tid >> 6, lane = tid & 63;
  int col16 = lane & 15, quad = lane >> 4;
  int g = wave & 1;                            // token half
  bool isq = wave < 2;
  int tok_l = g * 16 + col16;
  int n = n0 + tok_l;
  short8v bfr[8];
#pragma unroll
  for (int ks = 0; ks < 8; ++ks)
    bfr[ks] = ld8lds(&xs[tok_l * TP_ + ks * 32 + quad * 8]);

  const float* wrow = isq ? wq : wk;
  const float* bias = isq ? bq : bk;
  ushort_t* dst = isq ? qb : kb;
#pragma unroll
  for (int mt = 0; mt < 2; ++mt) {
    f32x4 c = {0.f, 0.f, 0.f, 0.f};
#pragma unroll
    for (int ks = 0; ks < 8; ++ks) {
      short8v afr = ld8f(wrow + (mt * 16 + col16) * C_ + ks * 32 + quad * 8);
      c = __builtin_amdgcn_mfma_f32_16x16x32_bf16(afr, bfr[ks], c, 0, 0, 0);
    }
    int co = mt * 16 + quad * 4;
    ushort4 pk;
    if (isq) {                                 // q pre-scaled by log2(e)
      pk.x = f2bf((c[0] + bias[co + 0]) * LOG2E);
      pk.y = f2bf((c[1] + bias[co + 1]) * LOG2E);
      pk.z = f2bf((c[2] + bias[co + 2]) * LOG2E);
      pk.w = f2bf((c[3] + bias[co + 3]) * LOG2E);
    } else {
      pk.x = f2bf(c[0] + bias[co + 0]); pk.y = f2bf(c[1] + bias[co + 1]);
      pk.z = f2bf(c[2] + bias[co + 2]); pk.w = f2bf(c[3] + bias[co + 3]);
    }
    *(ushort4*)(dst + ((size_t)(b * N_) + n) * CQK_ + co) = pk;
  }

  if (g0 != 0.0f) {                            // v projection (gamma != 0 only)
    int half = wave >> 1;
    for (int vt = 0; vt < 8; ++vt) {
      int tile = half * 8 + vt;
      f32x4 c = {0.f, 0.f, 0.f, 0.f};
#pragma unroll
      for (int ks = 0; ks < 8; ++ks) {
        short8v afr = ld8f(wv + (tile * 16 + col16) * C_ + ks * 32 + quad * 8);
        c = __builtin_amdgcn_mfma_f32_16x16x32_bf16(afr, bfr[ks], c, 0, 0, 0);
      }
      int co = tile * 16 + quad * 4;
      float4 o;
      o.x = c[0] + bv[co];     o.y = c[1] + bv[co + 1];
      o.z = c[2] + bv[co + 2]; o.w = c[3] + bv[co + 3];
      *(float4*)(v_t + ((size_t)(b * N_) + n) * C_ + co) = o;
    }
  }
}

// ---- phase A: l[b, i_base..+64) += sum over wave's column span ---------------
__device__ __forceinline__ void
phaseA(const ushort_t* __restrict__ qb, const ushort_t* __restrict__ kb,
       float* __restrict__ l, int b, int i_base, int j0, int tcnt, int tid) {
  int wave = tid >> 6, lane = tid & 63;
  int col16 = lane & 15, quad = lane >> 4;
  const ushort_t* qbb = qb + (size_t)b * N_ * CQK_;
  const ushort_t* kbb = kb + (size_t)b * N_ * CQK_;
  short8v a[4];
#pragma unroll
  for (int t = 0; t < 4; ++t)
    a[t] = *(const short8v*)(qbb + (i_base + t * 16 + col16) * CQK_ + quad * 8);
  float racc[16];
#pragma unroll
  for (int r = 0; r < 16; ++r) racc[r] = 0.0f;
  int j_base = j0 + wave * (tcnt * 16);
#pragma unroll 4
  for (int t = 0; t < tcnt; ++t) {
    short8v bfr = *(const short8v*)(kbb + (j_base + t * 16 + col16) * CQK_ + quad * 8);
#pragma unroll
    for (int m = 0; m < 4; ++m) {
      f32x4 c = {0.f, 0.f, 0.f, 0.f};
      c = __builtin_amdgcn_mfma_f32_16x16x32_bf16(a[m], bfr, c, 0, 0, 0);
      racc[m * 4 + 0] += __builtin_amdgcn_exp2f(c[0]);
      racc[m * 4 + 1] += __builtin_amdgcn_exp2f(c[1]);
      racc[m * 4 + 2] += __builtin_amdgcn_exp2f(c[2]);
      racc[m * 4 + 3] += __builtin_amdgcn_exp2f(c[3]);
    }
  }
#pragma unroll
  for (int r = 0; r < 16; ++r) {               // reduce over cols (lane&15)
    float v = racc[r];
    v += __shfl_xor(v, 1); v += __shfl_xor(v, 2);
    v += __shfl_xor(v, 4); v += __shfl_xor(v, 8);
    racc[r] = v;
  }
  if (col16 == 0) {
    float* lb = l + b * N_ + i_base;
#pragma unroll
    for (int m = 0; m < 4; ++m)
#pragma unroll
      for (int rr = 0; rr < 4; ++rr)
        atomicAdd(&lb[m * 16 + quad * 4 + rr], racc[m * 4 + rr]);
  }
}

// ---- phase B: map[jg*256 + wave*64 ..) += partial col sums over i span -------
__device__ __forceinline__ void
phaseB(const ushort_t* __restrict__ qb, const ushort_t* __restrict__ kb,
       const float* __restrict__ l, float* __restrict__ map,
       int b, int jg, int i_base, int tcnt, int tid) {
  int wave = tid >> 6, lane = tid & 63;
  int col16 = lane & 15, quad = lane >> 4;
  const ushort_t* qbb = qb + (size_t)b * N_ * CQK_;
  const ushort_t* kbb = kb + (size_t)b * N_ * CQK_;
  int j_base = jg * 256 + wave * 64;
  short8v a[4];                                // kT rows as A => D = S'^T tile
#pragma unroll
  for (int t = 0; t < 4; ++t)
    a[t] = *(const short8v*)(kbb + (j_base + t * 16 + col16) * CQK_ + quad * 8);
  float csum[16];
#pragma unroll
  for (int r = 0; r < 16; ++r) csum[r] = 0.0f;
#pragma unroll 4
  for (int t = 0; t < tcnt; ++t) {
    int i0 = i_base + t * 16;
    short8v bfr = *(const short8v*)(qbb + (i0 + col16) * CQK_ + quad * 8);
    float llog = -__builtin_amdgcn_logf(l[b * N_ + i0 + col16]);  // -log2(l_i)
    f32x4 cinit = {llog, llog, llog, llog};    // D cols = i -> fold 1/l_i here
#pragma unroll
    for (int m = 0; m < 4; ++m) {
      f32x4 c = __builtin_amdgcn_mfma_f32_16x16x32_bf16(a[m], bfr, cinit, 0, 0, 0);
      csum[m * 4 + 0] += __builtin_amdgcn_exp2f(c[0]);
      csum[m * 4 + 1] += __builtin_amdgcn_exp2f(c[1]);
      csum[m * 4 + 2] += __builtin_amdgcn_exp2f(c[2]);
      csum[m * 4 + 3] += __builtin_amdgcn_exp2f(c[3]);
    }
  }
#pragma unroll
  for (int r = 0; r < 16; ++r) {               // reduce over i (lane&15)
    float v = csum[r];
    v += __shfl_xor(v, 1); v += __shfl_xor(v, 2);
    v += __shfl_xor(v, 4); v += __shfl_xor(v, 8);
    csum[r] = v;
  }
  if (col16 == 0) {
    float* mp = map + b * N_ + j_base;
#pragma unroll
    for (int m = 0; m < 4; ++m)
#pragma unroll
      for (int rr = 0; rr < 4; ++rr)
        atomicAdd(&mp[m * 16 + quad * 4 + rr], csum[m * 4 + rr] * (1.0f / (float)N_));
  }
}

// ---- phase PV: 16-row i-tile of attended + residual (gamma != 0 only) --------
__device__ __forceinline__ void
phasePV(const ushort_t* __restrict__ qb, const ushort_t* __restrict__ kb,
        const float* __restrict__ v_t, const float* __restrict__ l, float g,
        float* __restrict__ out, int b, int i0, int jt_lo, int jt_hi,
        char* smem, int tid) {
  float* qs   = (float*)smem;                  // 16*32 fp32 = 2048 B
  float* invl = (float*)(smem + 2048);         // 64 B (+pad)
  float* ps   = (float*)(smem + 2176);         // 16*256 fp32 = 16384 B
  __syncthreads();
  for (int r = tid; r < 16 * CQK_; r += 256)
    qs[r] = bf2f(qb[((size_t)(b * N_) + i0) * CQK_ + r]);
  if (tid < 16) invl[tid] = 1.0f / l[b * N_ + i0 + tid];
  __syncthreads();
  float acc[16];
#pragma unroll
  for (int i = 0; i < 16; ++i) acc[i] = 0.0f;
  for (int jt = jt_lo; jt < jt_hi; ++jt) {
    int j = jt * 256 + tid;
    const ushort_t* krow = kb + ((size_t)(b * N_) + j) * CQK_;
    float kcol[CQK_];
#pragma unroll
    for (int o = 0; o < CQK_; ++o) kcol[o] = bf2f(krow[o]);
#pragma unroll
    for (int i = 0; i < 16; ++i) {
      float s = 0.0f;
#pragma unroll
      for (int o = 0; o < CQK_; ++o) s += qs[i * CQK_ + o] * kcol[o];
      ps[i * 256 + tid] = __builtin_amdgcn_exp2f(s) * invl[i];
    }
    __syncthreads();
    const float* vtb = v_t + ((size_t)(b * N_) + jt * 256) * C_;
    for (int jj = 0; jj < 256; ++jj) {
      float vv = vtb[(size_t)jj * C_ + tid];
#pragma unroll
      for (int i = 0; i < 16; ++i) acc[i] += ps[i * 256 + jj] * vv;
    }
    __syncthreads();
  }
  float* ob = out + ((size_t)(b * C_) + tid) * N_ + i0;
#pragma unroll
  for (int i = 0; i < 16; ++i) atomicAdd(&ob[i], g * acc[i]);
}

// ================= fused cooperative kernel (grid 512 x 256) =================
__global__ __launch_bounds__(256, 4) void
k_fused(const float* __restrict__ x,
        const float* __restrict__ wq, const float* __restrict__ bq,
        const float* __restrict__ wk, const float* __restrict__ bk,
        const float* __restrict__ wv, const float* __restrict__ bv,
        const float* __restrict__ gamma,
        float* __restrict__ out, float* __restrict__ l,
        ushort_t* __restrict__ qb, ushort_t* __restrict__ kb,
        float* __restrict__ v_t) {
  __shared__ __align__(16) char smem[SMEM_BYTES];
  cg::grid_group grid = cg::this_grid();
  int blk = blockIdx.x, tid = threadIdx.x;
  float g0 = gamma[0];

  phaseP(x, wq, bq, wk, bk, wv, bv, g0, out, l, qb, kb, v_t,
         (ushort_t*)smem, blk, tid);
  grid.sync();
  {
    int b = blk >> 7, rem = blk & 127;
    phaseA(qb, kb, l, b, (rem >> 1) * 64, (rem & 1) * 2048, 32, tid);
  }
  grid.sync();
  {
    int b = blk >> 7, rem = blk & 127;
    phaseB(qb, kb, l, out + BCN_, b, rem >> 3, (rem & 7) * 512, 32, tid);
  }
  if (g0 != 0.0f) {
    int b = blk >> 7, rem = blk & 127;
    for (int it2 = 0; it2 < 2; ++it2)
      phasePV(qb, kb, v_t, l, g0, out, b, rem * 32 + it2 * 16, 0, 16, smem, tid);
  }
}

// ================= fallback split kernels (R6 geometry) ======================
__global__ __launch_bounds__(256) void
k_prepS(const float* __restrict__ x, const float* __restrict__ wq,
        const float* __restrict__ bq, const float* __restrict__ wk,
        const float* __restrict__ bk, const float* __restrict__ wv,
        const float* __restrict__ bv, const float* __restrict__ gamma,
        float* __restrict__ out, float* __restrict__ l,
        ushort_t* __restrict__ qb, ushort_t* __restrict__ kb,
        float* __restrict__ v_t) {
  __shared__ __align__(16) char smem[32 * TP_ * 2];
  phaseP(x, wq, bq, wk, bk, wv, bv, gamma[0], out, l, qb, kb, v_t,
         (ushort_t*)smem, blockIdx.x, threadIdx.x);
}

__global__ __launch_bounds__(256) void
k_rowsS(const ushort_t* __restrict__ qb, const ushort_t* __restrict__ kb,
        float* __restrict__ l) {
  int blk = blockIdx.x;  // 1024: b(4) x rg(64) x js(4)
  phaseA(qb, kb, l, blk >> 8, ((blk >> 2) & 63) * 64, (blk & 3) * 1024, 16,
         threadIdx.x);
}

__global__ __launch_bounds__(256) void
k_mapS(const ushort_t* __restrict__ qb, const ushort_t* __restrict__ kb,
       const float* __restrict__ l, float* __restrict__ map) {
  int blk = blockIdx.x;  // 1024: b(4) x jg(16) x isp(16)
  phaseB(qb, kb, l, map, blk >> 8, (blk >> 4) & 15, (blk & 15) * 256, 16,
         threadIdx.x);
}

__global__ __launch_bounds__(256) void
k_pvS(const ushort_t* __restrict__ qb, const ushort_t* __restrict__ kb,
      const float* __restrict__ v_t, const float* __restrict__ l,
      const float* __restrict__ gamma, float* __restrict__ out) {
  float g = gamma[0];
  if (g == 0.0f) return;
  __shared__ __align__(16) char smem[SMEM_BYTES];
  int blk = blockIdx.x;  // 2048: b(4) x rem(128) x jsp(4)
  int b = blk >> 9, rem = (blk >> 2) & 127, jsp = blk & 3;
  for (int it2 = 0; it2 < 2; ++it2)
    phasePV(qb, kb, v_t, l, g, out, b, rem * 32 + it2 * 16,
            jsp * 4, jsp * 4 + 4, smem, threadIdx.x);
}

extern "C" void kernel_launch(void* const* d_in, const int* in_sizes, int n_in,
                              void* d_out, int out_size, void* d_ws, size_t ws_size,
                              hipStream_t stream) {
  const float* x     = (const float*)d_in[0];
  const float* wq    = (const float*)d_in[1];
  const float* bq    = (const float*)d_in[2];
  const float* wk    = (const float*)d_in[3];
  const float* bk    = (const float*)d_in[4];
  const float* wv    = (const float*)d_in[5];
  const float* bv    = (const float*)d_in[6];
  const float* gamma = (const float*)d_in[7];
  float* out = (float*)d_out;
  float* wsf = (float*)d_ws;
  // ws layout (float offsets): l 16384 | qb 262144 | kb 262144 | v_t 4194304
  float*    l   = wsf;
  ushort_t* qb  = (ushort_t*)(wsf + 16384);
  ushort_t* kb  = (ushort_t*)(wsf + 16384 + 262144);
  float*    v_t = wsf + 16384 + 2 * 262144;

  void* args[] = {(void*)&x, (void*)&wq, (void*)&bq, (void*)&wk, (void*)&bk,
                  (void*)&wv, (void*)&bv, (void*)&gamma, (void*)&out,
                  (void*)&l, (void*)&qb, (void*)&kb, (void*)&v_t};
  hipError_t err = hipLaunchCooperativeKernel((const void*)k_fused, dim3(512),
                                              dim3(256), args, 0, stream);
  if (err != hipSuccess) {   // fallback: proven 4-kernel split path
    k_prepS<<< 512, 256, 0, stream>>>(x, wq, bq, wk, bk, wv, bv, gamma,
                                      out, l, qb, kb, v_t);
    k_rowsS<<<1024, 256, 0, stream>>>(qb, kb, l);
    k_mapS <<<1024, 256, 0, stream>>>(qb, kb, l, out + BCN_);
    k_pvS  <<<2048, 256, 0, stream>>>(qb, kb, v_t, l, gamma, out);
  }
}

// Round 10
// 123.727 us; speedup vs baseline: 1.9142x; 1.9142x over previous
//
#include <hip/hip_runtime.h>

// SpatialAttention: B=4, C=256, H=W=64 -> N=4096, C_qk=32
// d_out: [output (4*256*4096)] ++ [attention_map (4*4096)]  (fp32)
//
// Structure: S=q.kT (K=32) = one mfma_f32_16x16x32_bf16 per 16x16 tile; q,kT
// token-major bf16. Two passes over S (rowsums l, col-means map). gamma==0
// (test data) => output==x; v/PV paths early-exit but are implemented.
// q pre-scaled by log2(e) -> raw v_exp_f32 (2^x); mapB folds -log2(l_i) into
// the MFMA C-init.
// R9 showed cooperative grid.sync costs ~110us (VALUBusy 9%) — far more than
// the ~6us of launch gaps it removes. R10: revert to the proven split path
// (R6 = 122.5us), minus one launch: PV phase merged into the map kernel.

#define B_   4
#define C_   256
#define N_   4096
#define CQK_ 32
#define BCN_ (B_*C_*N_)   // 4194304
#define BN_  (B_*N_)      // 16384
#define TP_  260          // LDS token-row pitch (ushorts)
#define LOG2E 1.4426950408889634f
#define SMEM_PV 18560

typedef __attribute__((ext_vector_type(8))) short short8v;
typedef __attribute__((ext_vector_type(4))) short short4v;
typedef __attribute__((ext_vector_type(4))) float f32x4;
typedef unsigned short ushort_t;

__device__ __forceinline__ ushort_t f2bf(float f) {
  unsigned u = __builtin_bit_cast(unsigned, f);
  u += 0x7FFFu + ((u >> 16) & 1u);          // round-to-nearest-even
  return (ushort_t)(u >> 16);
}
__device__ __forceinline__ float bf2f(ushort_t h) {
  unsigned u = ((unsigned)h) << 16;
  return __builtin_bit_cast(float, u);
}
__device__ __forceinline__ short8v ld8f(const float* p) {   // 8 fp32 -> bf16 frag
  float4 a = *(const float4*)p, b = *(const float4*)(p + 4);
  short8v r;
  r[0]=f2bf(a.x); r[1]=f2bf(a.y); r[2]=f2bf(a.z); r[3]=f2bf(a.w);
  r[4]=f2bf(b.x); r[5]=f2bf(b.y); r[6]=f2bf(b.z); r[7]=f2bf(b.w);
  return r;
}
__device__ __forceinline__ short8v ld8lds(const ushort_t* p) {  // 8B-aligned LDS
  short4v lo = *(const short4v*)p, hi = *(const short4v*)(p + 4);
  return __builtin_shufflevector(lo, hi, 0, 1, 2, 3, 4, 5, 6, 7);
}

// ---- phase P: out=x copy, q/k (+v) projections, init l/map ------------------
__device__ __forceinline__ void
phaseP(const float* __restrict__ x, const float* __restrict__ wq,
       const float* __restrict__ bq, const float* __restrict__ wk,
       const float* __restrict__ bk, const float* __restrict__ wv,
       const float* __restrict__ bv, float g0,
       float* __restrict__ out, float* __restrict__ l,
       ushort_t* __restrict__ qb, ushort_t* __restrict__ kb,
       float* __restrict__ v_t, ushort_t* xs, int blk, int tid) {
  int b = blk >> 7, n0 = (blk & 127) << 5;     // 32 tokens/block
#pragma unroll
  for (int it = 0; it < 8; ++it) {             // 2048 float4s: 256ch x 32tok
    int flat = it * 256 + tid;
    int c = flat >> 3, t4 = flat & 7;
    size_t off = ((size_t)(b * C_) + c) * N_ + n0 + t4 * 4;
    float4 v = *(const float4*)(x + off);
    *(float4*)(out + off) = v;
    ushort_t* dst = &xs[(t4 * 4) * TP_ + c];
    dst[0]       = f2bf(v.x);
    dst[TP_]     = f2bf(v.y);
    dst[2 * TP_] = f2bf(v.z);
    dst[3 * TP_] = f2bf(v.w);
  }
  if (blk < 64) {                              // zero l + attention_map
    int idx = blk * 256 + tid;
    l[idx] = 0.0f;
    out[BCN_ + idx] = 0.0f;
  }
  __syncthreads();

  int wave = tid >> 6, lane = tid & 63;
  int col16 = lane & 15, quad = lane >> 4;
  int g = wave & 1;                            // token half
  bool isq = wave < 2;
  int tok_l = g * 16 + col16;
  int n = n0 + tok_l;
  short8v bfr[8];
#pragma unroll
  for (int ks = 0; ks < 8; ++ks)
    bfr[ks] = ld8lds(&xs[tok_l * TP_ + ks * 32 + quad * 8]);

  const float* wrow = isq ? wq : wk;
  const float* bias = isq ? bq : bk;
  ushort_t* dst = isq ? qb : kb;
#pragma unroll
  for (int mt = 0; mt < 2; ++mt) {
    f32x4 c = {0.f, 0.f, 0.f, 0.f};
#pragma unroll
    for (int ks = 0; ks < 8; ++ks) {
      short8v afr = ld8f(wrow + (mt * 16 + col16) * C_ + ks * 32 + quad * 8);
      c = __builtin_amdgcn_mfma_f32_16x16x32_bf16(afr, bfr[ks], c, 0, 0, 0);
    }
    int co = mt * 16 + quad * 4;
    ushort4 pk;
    if (isq) {                                 // q pre-scaled by log2(e)
      pk.x = f2bf((c[0] + bias[co + 0]) * LOG2E);
      pk.y = f2bf((c[1] + bias[co + 1]) * LOG2E);
      pk.z = f2bf((c[2] + bias[co + 2]) * LOG2E);
      pk.w = f2bf((c[3] + bias[co + 3]) * LOG2E);
    } else {
      pk.x = f2bf(c[0] + bias[co + 0]); pk.y = f2bf(c[1] + bias[co + 1]);
      pk.z = f2bf(c[2] + bias[co + 2]); pk.w = f2bf(c[3] + bias[co + 3]);
    }
    *(ushort4*)(dst + ((size_t)(b * N_) + n) * CQK_ + co) = pk;
  }

  if (g0 != 0.0f) {                            // v projection (gamma != 0 only)
    int half = wave >> 1;
    for (int vt = 0; vt < 8; ++vt) {
      int tile = half * 8 + vt;
      f32x4 c = {0.f, 0.f, 0.f, 0.f};
#pragma unroll
      for (int ks = 0; ks < 8; ++ks) {
        short8v afr = ld8f(wv + (tile * 16 + col16) * C_ + ks * 32 + quad * 8);
        c = __builtin_amdgcn_mfma_f32_16x16x32_bf16(afr, bfr[ks], c, 0, 0, 0);
      }
      int co = tile * 16 + quad * 4;
      float4 o;
      o.x = c[0] + bv[co];     o.y = c[1] + bv[co + 1];
      o.z = c[2] + bv[co + 2]; o.w = c[3] + bv[co + 3];
      *(float4*)(v_t + ((size_t)(b * N_) + n) * C_ + co) = o;
    }
  }
}

// ---- phase A: l[b, i_base..+64) += sum over wave's column span --------------
__device__ __forceinline__ void
phaseA(const ushort_t* __restrict__ qb, const ushort_t* __restrict__ kb,
       float* __restrict__ l, int b, int i_base, int j0, int tcnt, int tid) {
  int wave = tid >> 6, lane = tid & 63;
  int col16 = lane & 15, quad = lane >> 4;
  const ushort_t* qbb = qb + (size_t)b * N_ * CQK_;
  const ushort_t* kbb = kb + (size_t)b * N_ * CQK_;
  short8v a[4];
#pragma unroll
  for (int t = 0; t < 4; ++t)
    a[t] = *(const short8v*)(qbb + (i_base + t * 16 + col16) * CQK_ + quad * 8);
  float racc[16];
#pragma unroll
  for (int r = 0; r < 16; ++r) racc[r] = 0.0f;
  int j_base = j0 + wave * (tcnt * 16);
#pragma unroll 4
  for (int t = 0; t < tcnt; ++t) {
    short8v bfr = *(const short8v*)(kbb + (j_base + t * 16 + col16) * CQK_ + quad * 8);
#pragma unroll
    for (int m = 0; m < 4; ++m) {
      f32x4 c = {0.f, 0.f, 0.f, 0.f};
      c = __builtin_amdgcn_mfma_f32_16x16x32_bf16(a[m], bfr, c, 0, 0, 0);
      racc[m * 4 + 0] += __builtin_amdgcn_exp2f(c[0]);
      racc[m * 4 + 1] += __builtin_amdgcn_exp2f(c[1]);
      racc[m * 4 + 2] += __builtin_amdgcn_exp2f(c[2]);
      racc[m * 4 + 3] += __builtin_amdgcn_exp2f(c[3]);
    }
  }
#pragma unroll
  for (int r = 0; r < 16; ++r) {               // reduce over cols (lane&15)
    float v = racc[r];
    v += __shfl_xor(v, 1); v += __shfl_xor(v, 2);
    v += __shfl_xor(v, 4); v += __shfl_xor(v, 8);
    racc[r] = v;
  }
  if (col16 == 0) {
    float* lb = l + b * N_ + i_base;
#pragma unroll
    for (int m = 0; m < 4; ++m)
#pragma unroll
      for (int rr = 0; rr < 4; ++rr)
        atomicAdd(&lb[m * 16 + quad * 4 + rr], racc[m * 4 + rr]);
  }
}

// ---- phase B: map[jg*256 + wave*64 ..) += partial col sums over i span ------
__device__ __forceinline__ void
phaseB(const ushort_t* __restrict__ qb, const ushort_t* __restrict__ kb,
       const float* __restrict__ l, float* __restrict__ map,
       int b, int jg, int i_base, int tcnt, int tid) {
  int wave = tid >> 6, lane = tid & 63;
  int col16 = lane & 15, quad = lane >> 4;
  const ushort_t* qbb = qb + (size_t)b * N_ * CQK_;
  const ushort_t* kbb = kb + (size_t)b * N_ * CQK_;
  int j_base = jg * 256 + wave * 64;
  short8v a[4];                                // kT rows as A => D = S'^T tile
#pragma unroll
  for (int t = 0; t < 4; ++t)
    a[t] = *(const short8v*)(kbb + (j_base + t * 16 + col16) * CQK_ + quad * 8);
  float csum[16];
#pragma unroll
  for (int r = 0; r < 16; ++r) csum[r] = 0.0f;
#pragma unroll 4
  for (int t = 0; t < tcnt; ++t) {
    int i0 = i_base + t * 16;
    short8v bfr = *(const short8v*)(qbb + (i0 + col16) * CQK_ + quad * 8);
    float llog = -__builtin_amdgcn_logf(l[b * N_ + i0 + col16]);  // -log2(l_i)
    f32x4 cinit = {llog, llog, llog, llog};    // D cols = i -> fold 1/l_i here
#pragma unroll
    for (int m = 0; m < 4; ++m) {
      f32x4 c = __builtin_amdgcn_mfma_f32_16x16x32_bf16(a[m], bfr, cinit, 0, 0, 0);
      csum[m * 4 + 0] += __builtin_amdgcn_exp2f(c[0]);
      csum[m * 4 + 1] += __builtin_amdgcn_exp2f(c[1]);
      csum[m * 4 + 2] += __builtin_amdgcn_exp2f(c[2]);
      csum[m * 4 + 3] += __builtin_amdgcn_exp2f(c[3]);
    }
  }
#pragma unroll
  for (int r = 0; r < 16; ++r) {               // reduce over i (lane&15)
    float v = csum[r];
    v += __shfl_xor(v, 1); v += __shfl_xor(v, 2);
    v += __shfl_xor(v, 4); v += __shfl_xor(v, 8);
    csum[r] = v;
  }
  if (col16 == 0) {
    float* mp = map + b * N_ + j_base;
#pragma unroll
    for (int m = 0; m < 4; ++m)
#pragma unroll
      for (int rr = 0; rr < 4; ++rr)
        atomicAdd(&mp[m * 16 + quad * 4 + rr], csum[m * 4 + rr] * (1.0f / (float)N_));
  }
}

// ---- phase PV: 16-row i-tile of attended + residual (gamma != 0 only) -------
__device__ __forceinline__ void
phasePV(const ushort_t* __restrict__ qb, const ushort_t* __restrict__ kb,
        const float* __restrict__ v_t, const float* __restrict__ l, float g,
        float* __restrict__ out, int b, int i0, int jt_lo, int jt_hi,
        char* smem, int tid) {
  float* qs   = (float*)smem;                  // 16*32 fp32 = 2048 B
  float* invl = (float*)(smem + 2048);         // 64 B (+pad)
  float* ps   = (float*)(smem + 2176);         // 16*256 fp32 = 16384 B
  __syncthreads();
  for (int r = tid; r < 16 * CQK_; r += 256)
    qs[r] = bf2f(qb[((size_t)(b * N_) + i0) * CQK_ + r]);
  if (tid < 16) invl[tid] = 1.0f / l[b * N_ + i0 + tid];
  __syncthreads();
  float acc[16];
#pragma unroll
  for (int i = 0; i < 16; ++i) acc[i] = 0.0f;
  for (int jt = jt_lo; jt < jt_hi; ++jt) {
    int j = jt * 256 + tid;
    const ushort_t* krow = kb + ((size_t)(b * N_) + j) * CQK_;
    float kcol[CQK_];
#pragma unroll
    for (int o = 0; o < CQK_; ++o) kcol[o] = bf2f(krow[o]);
#pragma unroll
    for (int i = 0; i < 16; ++i) {
      float s = 0.0f;
#pragma unroll
      for (int o = 0; o < CQK_; ++o) s += qs[i * CQK_ + o] * kcol[o];
      ps[i * 256 + tid] = __builtin_amdgcn_exp2f(s) * invl[i];
    }
    __syncthreads();
    const float* vtb = v_t + ((size_t)(b * N_) + jt * 256) * C_;
    for (int jj = 0; jj < 256; ++jj) {
      float vv = vtb[(size_t)jj * C_ + tid];
#pragma unroll
      for (int i = 0; i < 16; ++i) acc[i] += ps[i * 256 + jj] * vv;
    }
    __syncthreads();
  }
  float* ob = out + ((size_t)(b * C_) + tid) * N_ + i0;
#pragma unroll
  for (int i = 0; i < 16; ++i) atomicAdd(&ob[i], g * acc[i]);
}

// ================= split kernels =============================================
__global__ __launch_bounds__(256) void
k_prepS(const float* __restrict__ x, const float* __restrict__ wq,
        const float* __restrict__ bq, const float* __restrict__ wk,
        const float* __restrict__ bk, const float* __restrict__ wv,
        const float* __restrict__ bv, const float* __restrict__ gamma,
        float* __restrict__ out, float* __restrict__ l,
        ushort_t* __restrict__ qb, ushort_t* __restrict__ kb,
        float* __restrict__ v_t) {
  __shared__ __align__(16) char smem[32 * TP_ * 2];
  phaseP(x, wq, bq, wk, bk, wv, bv, gamma[0], out, l, qb, kb, v_t,
         (ushort_t*)smem, blockIdx.x, threadIdx.x);
}

__global__ __launch_bounds__(256) void
k_rowsS(const ushort_t* __restrict__ qb, const ushort_t* __restrict__ kb,
        float* __restrict__ l) {
  int blk = blockIdx.x;  // 1024: b(4) x rg(64) x js(4)
  phaseA(qb, kb, l, blk >> 8, ((blk >> 2) & 63) * 64, (blk & 3) * 1024, 16,
         threadIdx.x);
}

__global__ __launch_bounds__(256) void
k_mapS(const ushort_t* __restrict__ qb, const ushort_t* __restrict__ kb,
       const float* __restrict__ v_t, const float* __restrict__ l,
       const float* __restrict__ gamma, float* __restrict__ out) {
  __shared__ __align__(16) char smem[SMEM_PV];
  int blk = blockIdx.x;  // 1024: b(4) x jg(16) x isp(16)
  int b = blk >> 8;
  phaseB(qb, kb, l, out + BCN_, b, (blk >> 4) & 15, (blk & 15) * 256, 16,
         threadIdx.x);
  float g = gamma[0];
  if (g != 0.0f)         // PV: 256 i-tiles of 16 rows x full j per batch
    phasePV(qb, kb, v_t, l, g, out, b, (blk & 255) * 16, 0, 16, smem,
            threadIdx.x);
}

extern "C" void kernel_launch(void* const* d_in, const int* in_sizes, int n_in,
                              void* d_out, int out_size, void* d_ws, size_t ws_size,
                              hipStream_t stream) {
  const float* x     = (const float*)d_in[0];
  const float* wq    = (const float*)d_in[1];
  const float* bq    = (const float*)d_in[2];
  const float* wk    = (const float*)d_in[3];
  const float* bk    = (const float*)d_in[4];
  const float* wv    = (const float*)d_in[5];
  const float* bv    = (const float*)d_in[6];
  const float* gamma = (const float*)d_in[7];
  float* out = (float*)d_out;
  float* wsf = (float*)d_ws;
  // ws layout (float offsets): l 16384 | qb 262144 | kb 262144 | v_t 4194304
  float*    l   = wsf;
  ushort_t* qb  = (ushort_t*)(wsf + 16384);
  ushort_t* kb  = (ushort_t*)(wsf + 16384 + 262144);
  float*    v_t = wsf + 16384 + 2 * 262144;

  k_prepS<<< 512, 256, 0, stream>>>(x, wq, bq, wk, bk, wv, bv, gamma,
                                    out, l, qb, kb, v_t);
  k_rowsS<<<1024, 256, 0, stream>>>(qb, kb, l);
  k_mapS <<<1024, 256, 0, stream>>>(qb, kb, v_t, l, gamma, out);
}